// Round 7
// baseline (1018.705 us; speedup 1.0000x reference)
//
#include <hip/hip_runtime.h>
#include <cstdint>
#include <cstddef>

// DecoderBlock on MI355X (gfx950), round 7 (= round 6 resubmit after infra fail).
// - 2-pass bf16 split GEMM (A = Ah+Al, W = bf16(W)), glds staging, 128x128.
//   Grid-starvation fix: merged FFN (W1 N=4096, W2 K=4096 z=4), Wo z=4,
//   caQ z=4 + cast. All big GEMMs >= 1024 blocks.
// - Attention: QBLK=128, KVBLK=64, dbuf, swizzled K, stride-68 P relay,
//   K pre-scaled by 1/8 at weight-cast (softmax scale free), T13 defer-
//   rescale (threshold 5), deferred l-reduction, setprio.

typedef __bf16 bf16;
typedef __attribute__((ext_vector_type(4))) float f32x4;
typedef __attribute__((ext_vector_type(8))) __bf16 bf16x8;
typedef __attribute__((ext_vector_type(4))) __bf16 bf16x4;
typedef __attribute__((ext_vector_type(2))) __bf16 bf16x2;

#define MFMA(a, b, c) __builtin_amdgcn_mfma_f32_16x16x32_bf16((a), (b), (c), 0, 0, 0)

constexpr int D_MODEL = 1024;
constexpr int S_LEN   = 2048;
constexpr int BATCH   = 2;
constexpr int M_ROWS  = S_LEN * BATCH;  // 4096

struct bfp { bf16 h, l; };
__device__ __forceinline__ bfp fsplit(float f) {
  bfp r;
  r.h = (bf16)f;
  r.l = (bf16)(f - (float)r.h);
  return r;
}

typedef const void __attribute__((address_space(1))) gas_void;
typedef void __attribute__((address_space(3))) las_void;
__device__ __forceinline__ void glds16(const void* g, void* l) {
  __builtin_amdgcn_global_load_lds((gas_void*)g, (las_void*)l, 16, 0, 0);
}

// ---------------------------------------------------------------------------
// Weight cast + transpose + scale: W[K][N] fp32 -> Th[N][K] bf16 * sc
// ---------------------------------------------------------------------------
__global__ void wcast_t(const float* __restrict__ W, bf16* __restrict__ Th,
                        int K, int N, float sc) {
  __shared__ float t[32][33];
  const int kt = blockIdx.x * 32, nt = blockIdx.y * 32;
  const int tx = threadIdx.x, ty = threadIdx.y;  // 32 x 8
#pragma unroll
  for (int i = 0; i < 4; ++i)
    t[ty * 4 + i][tx] = W[(size_t)(kt + ty * 4 + i) * N + nt + tx];
  __syncthreads();
#pragma unroll
  for (int i = 0; i < 4; ++i) {
    int n = nt + ty * 4 + i;
    Th[(size_t)n * K + kt + tx] = (bf16)(t[tx][ty * 4 + i] * sc);
  }
}

// ---------------------------------------------------------------------------
__global__ void scale_copy(const float* __restrict__ S, float* __restrict__ D,
                           float sc) {
  const int i = blockIdx.x * 256 + threadIdx.x;
  D[i] = S[i] * sc;
}

__global__ void act_split(const float* __restrict__ X, bf16* __restrict__ H,
                          bf16* __restrict__ L) {
  const size_t i = ((size_t)blockIdx.x * 256 + threadIdx.x) * 4;
  float4 v = *reinterpret_cast<const float4*>(&X[i]);
  bf16x4 h, l;
  bfp s0 = fsplit(v.x); h[0] = s0.h; l[0] = s0.l;
  bfp s1 = fsplit(v.y); h[1] = s1.h; l[1] = s1.l;
  bfp s2 = fsplit(v.z); h[2] = s2.h; l[2] = s2.l;
  bfp s3 = fsplit(v.w); h[3] = s3.h; l[3] = s3.l;
  *reinterpret_cast<bf16x4*>(&H[i]) = h;
  *reinterpret_cast<bf16x4*>(&L[i]) = l;
}

__global__ void cast_bf16(const float* __restrict__ X, bf16* __restrict__ H) {
  const size_t i = ((size_t)blockIdx.x * 256 + threadIdx.x) * 4;
  float4 v = *reinterpret_cast<const float4*>(&X[i]);
  bf16x4 h;
  h[0] = (bf16)v.x; h[1] = (bf16)v.y; h[2] = (bf16)v.z; h[3] = (bf16)v.w;
  *reinterpret_cast<bf16x4*>(&H[i]) = h;
}

// ---------------------------------------------------------------------------
// 2-pass split GEMM. A = Ah+Al [M][K] bf16, B = Bh [N][ldb] bf16 (transposed).
// flags: 1 relu, 2 f32-atomic-acc, 4 bf16 out, 8 split out, 16 add bias
// (z==0 only). K-split via gridDim.z.
// ---------------------------------------------------------------------------
__launch_bounds__(256)
__global__ void gemm_split(const bf16* __restrict__ Ah_g, const bf16* __restrict__ Al_g,
                           const bf16* __restrict__ Bh_g,
                           const float* __restrict__ bias,
                           float* Cf, bf16* Ch, bf16* Cl,
                           int N, int K, int ldb, int flags) {
  __shared__ bf16 sAh[4096], sAl[4096], sBh[4096];  // [128][32] each
  const int tid = threadIdx.x, ln = tid & 63, w = tid >> 6;
  const int g = ln >> 4, lr = ln & 15;
  const int wr = w >> 1, wc = w & 1;
  const int m0 = blockIdx.y * 128, n0 = blockIdx.x * 128;
  const int kz = K / gridDim.z;
  const int kbeg = blockIdx.z * kz, kend = kbeg + kz;

  f32x4 acc[4][4] = {};

  for (int k0 = kbeg; k0 < kend; k0 += 32) {
    __syncthreads();
#pragma unroll
    for (int i = 0; i < 2; ++i) {
      const int r = w * 32 + i * 16 + (ln >> 2);
      const int co = (ln & 3) * 8;
      const int lb = (w * 32 + i * 16) * 32;
      glds16(Ah_g + (size_t)(m0 + r) * K + k0 + co, &sAh[lb]);
      glds16(Al_g + (size_t)(m0 + r) * K + k0 + co, &sAl[lb]);
      glds16(Bh_g + (size_t)(n0 + r) * ldb + k0 + co, &sBh[lb]);
    }
    __syncthreads();

    bf16x8 ah[4], al[4], bh[4];
#pragma unroll
    for (int mi = 0; mi < 4; ++mi) {
      const int r = wr * 64 + mi * 16 + lr;
      ah[mi] = *reinterpret_cast<const bf16x8*>(&sAh[r * 32 + g * 8]);
      al[mi] = *reinterpret_cast<const bf16x8*>(&sAl[r * 32 + g * 8]);
    }
#pragma unroll
    for (int ni = 0; ni < 4; ++ni) {
      const int r = wc * 64 + ni * 16 + lr;
      bh[ni] = *reinterpret_cast<const bf16x8*>(&sBh[r * 32 + g * 8]);
    }
#pragma unroll
    for (int mi = 0; mi < 4; ++mi)
#pragma unroll
      for (int ni = 0; ni < 4; ++ni) {
        acc[mi][ni] = MFMA(ah[mi], bh[ni], acc[mi][ni]);
        acc[mi][ni] = MFMA(al[mi], bh[ni], acc[mi][ni]);
      }
  }

#pragma unroll
  for (int mi = 0; mi < 4; ++mi)
#pragma unroll
    for (int ni = 0; ni < 4; ++ni) {
      const int col = n0 + wc * 64 + ni * 16 + lr;
      const float bv = ((flags & 16) && blockIdx.z == 0) ? bias[col] : 0.f;
#pragma unroll
      for (int r = 0; r < 4; ++r) {
        const int row = m0 + wr * 64 + mi * 16 + g * 4 + r;
        float v = acc[mi][ni][r] + bv;
        if (flags & 1) v = fmaxf(v, 0.f);
        const size_t off = (size_t)row * N + col;
        if (flags & 2) {
          atomicAdd(&Cf[off], v);
        } else if (flags & 4) {
          Ch[off] = (bf16)v;
        } else if (flags & 8) {
          bfp sp = fsplit(v);
          Ch[off] = sp.h;
          Cl[off] = sp.l;
        } else {
          Cf[off] = v;
        }
      }
    }
}

// ---------------------------------------------------------------------------
// Flash attention. bf16 in (K pre-scaled by 1/8), split-bf16 CTX out.
// Grid (S/128, BATCH*NHEAD), 256 thr. Wave w owns 32 q-rows q0 = qt*128+w*32.
// ---------------------------------------------------------------------------
__launch_bounds__(256)
__global__ void attn_kernel(const bf16* __restrict__ Qg, const bf16* __restrict__ Kg,
                            const bf16* __restrict__ Vg, int qs, int kvs,
                            bf16* __restrict__ Ch, bf16* __restrict__ Cl, int causal) {
  __shared__ bf16 Kl[2][64 * 64];   // swizzled, glds
  __shared__ bf16 Vt[2][64][72];    // [d][key]
  __shared__ bf16 Pl[4][32][68];    // per-wave P relay, stride 68
  const int tid = threadIdx.x, ln = tid & 63, w = tid >> 6;
  const int g = ln >> 4, lr = ln & 15;
  const int qt = blockIdx.x, bh = blockIdx.y;
  const int b = bh >> 4, h = bh & 15;
  const int q0 = qt * 128 + w * 32;

  const int krow8 = ln >> 3, d8 = ln & 7;   // K staging
  const int dq = tid >> 4, kp = tid & 15;   // V staging

  bf16x8 aq[2][2];
#pragma unroll
  for (int mf = 0; mf < 2; ++mf)
#pragma unroll
    for (int kk = 0; kk < 2; ++kk)
      aq[mf][kk] = *reinterpret_cast<const bf16x8*>(
          &Qg[((size_t)(q0 + mf * 16 + lr) * BATCH + b) * qs + h * 64 + kk * 32 + g * 8]);

  f32x4 acco[2][4] = {};
  float mrun[2][4], lrun[2][4];
#pragma unroll
  for (int mf = 0; mf < 2; ++mf)
#pragma unroll
    for (int r = 0; r < 4; ++r) { mrun[mf][r] = -1e30f; lrun[mf][r] = 0.f; }

  const int nkv = causal ? (qt * 2 + 2) : (S_LEN / 64);

  bf16x4 vreg[2][2];
  auto stageK = [&](int kv0, bf16* dst) {
#pragma unroll
    for (int i = 0; i < 2; ++i) {
      const int rbase = i * 32 + w * 8;
      const int row = rbase + krow8;
      glds16(Kg + (size_t)((kv0 + row) * BATCH + b) * kvs + h * 64 + ((d8 ^ (row & 7)) << 3),
             dst + rbase * 64);
    }
  };
  auto loadV = [&](int kv0) {
#pragma unroll
    for (int p = 0; p < 2; ++p) {
      const int k0v = p * 32 + kp * 2;
      vreg[p][0] = *reinterpret_cast<const bf16x4*>(
          &Vg[(size_t)((kv0 + k0v) * BATCH + b) * kvs + h * 64 + dq * 4]);
      vreg[p][1] = *reinterpret_cast<const bf16x4*>(
          &Vg[(size_t)((kv0 + k0v + 1) * BATCH + b) * kvs + h * 64 + dq * 4]);
    }
  };
  auto writeV = [&](int buf) {
#pragma unroll
    for (int p = 0; p < 2; ++p) {
      const int k0v = p * 32 + kp * 2;
#pragma unroll
      for (int i = 0; i < 4; ++i) {
        bf16x2 t2;
        t2[0] = vreg[p][0][i];
        t2[1] = vreg[p][1][i];
        *reinterpret_cast<bf16x2*>(&Vt[buf][dq * 4 + i][k0v]) = t2;
      }
    }
  };

  stageK(0, Kl[0]);
  loadV(0);
  writeV(0);
  __syncthreads();

  for (int kv = 0; kv < nkv; ++kv) {
    const int cur = kv & 1;
    const bool pre = (kv + 1 < nkv);
    if (pre) {  // issue next-tile loads early (T14)
      stageK((kv + 1) * 64, Kl[cur ^ 1]);
      loadV((kv + 1) * 64);
    }
    const int kv0 = kv * 64;

    if (!(causal && kv0 > q0 + 31)) {
      const char* kbase = (const char*)Kl[cur];
      // S = Q K^T (K pre-scaled by 1/8)
      f32x4 s[2][4];
      __builtin_amdgcn_s_setprio(1);
#pragma unroll
      for (int mf = 0; mf < 2; ++mf)
#pragma unroll
        for (int c = 0; c < 4; ++c) {
          f32x4 a = {};
#pragma unroll
          for (int kk = 0; kk < 2; ++kk) {
            bf16x8 bk = *reinterpret_cast<const bf16x8*>(
                kbase + (c * 16 + lr) * 128 + ((((kk << 2) + g) ^ (lr & 7)) << 4));
            a = MFMA(aq[mf][kk], bk, a);
          }
          s[mf][c] = a;
        }
      __builtin_amdgcn_s_setprio(0);

      if (causal && kv0 + 63 > q0) {
#pragma unroll
        for (int mf = 0; mf < 2; ++mf)
#pragma unroll
          for (int c = 0; c < 4; ++c) {
            const int key = kv0 + c * 16 + lr;
#pragma unroll
            for (int r = 0; r < 4; ++r)
              if (key > q0 + mf * 16 + g * 4 + r) s[mf][c][r] = -1e30f;
          }
      }

      // T13 defer-rescale: only rescale when some lane's local max grows >5
      float lm[2][4];
      bool need = false;
#pragma unroll
      for (int mf = 0; mf < 2; ++mf)
#pragma unroll
        for (int r = 0; r < 4; ++r) {
          lm[mf][r] = fmaxf(fmaxf(s[mf][0][r], s[mf][1][r]),
                            fmaxf(s[mf][2][r], s[mf][3][r]));
          need = need || (lm[mf][r] > mrun[mf][r] + 5.f);
        }
      if (__any(need)) {
#pragma unroll
        for (int mf = 0; mf < 2; ++mf)
#pragma unroll
          for (int r = 0; r < 4; ++r) {
            float mx = lm[mf][r];
#pragma unroll
            for (int off = 8; off >= 1; off >>= 1) mx = fmaxf(mx, __shfl_xor(mx, off));
            const float mnew = fmaxf(mrun[mf][r], mx);
            const float sf = __expf(mrun[mf][r] - mnew);
            lrun[mf][r] *= sf;
            mrun[mf][r] = mnew;
#pragma unroll
            for (int t = 0; t < 4; ++t) acco[mf][t][r] *= sf;
          }
      }
#pragma unroll
      for (int mf = 0; mf < 2; ++mf)
#pragma unroll
        for (int r = 0; r < 4; ++r) {
          float pv[4], ps = 0.f;
#pragma unroll
          for (int c = 0; c < 4; ++c) { pv[c] = __expf(s[mf][c][r] - mrun[mf][r]); ps += pv[c]; }
          lrun[mf][r] += ps;
#pragma unroll
          for (int c = 0; c < 4; ++c) Pl[w][mf * 16 + g * 4 + r][c * 16 + lr] = (bf16)pv[c];
        }

      // O += P V
      __builtin_amdgcn_s_setprio(1);
#pragma unroll
      for (int mf = 0; mf < 2; ++mf) {
        bf16x8 ap0 = *reinterpret_cast<const bf16x8*>(&Pl[w][mf * 16 + lr][g * 8]);
        bf16x8 ap1 = *reinterpret_cast<const bf16x8*>(&Pl[w][mf * 16 + lr][32 + g * 8]);
#pragma unroll
        for (int t = 0; t < 4; ++t) {
          bf16x8 v0 = *reinterpret_cast<const bf16x8*>(&Vt[cur][t * 16 + lr][g * 8]);
          bf16x8 v1 = *reinterpret_cast<const bf16x8*>(&Vt[cur][t * 16 + lr][32 + g * 8]);
          acco[mf][t] = MFMA(ap0, v0, acco[mf][t]);
          acco[mf][t] = MFMA(ap1, v1, acco[mf][t]);
        }
      }
      __builtin_amdgcn_s_setprio(0);
    }

    if (pre) writeV(cur ^ 1);  // write-late
    __syncthreads();
  }

  // epilogue: finish l reduction, normalize, split-store
#pragma unroll
  for (int mf = 0; mf < 2; ++mf)
#pragma unroll
    for (int r = 0; r < 4; ++r) {
      float l = lrun[mf][r];
#pragma unroll
      for (int off = 8; off >= 1; off >>= 1) l += __shfl_xor(l, off);
      lrun[mf][r] = 1.f / l;
    }
#pragma unroll
  for (int mf = 0; mf < 2; ++mf)
#pragma unroll
    for (int t = 0; t < 4; ++t)
#pragma unroll
      for (int r = 0; r < 4; ++r) {
        const int srow = q0 + mf * 16 + g * 4 + r;
        const size_t off = (size_t)(srow * BATCH + b) * D_MODEL + h * 64 + t * 16 + lr;
        const float v = acco[mf][t][r] * lrun[mf][r];
        bfp sp = fsplit(v);
        Ch[off] = sp.h;
        Cl[off] = sp.l;
      }
}

// ---------------------------------------------------------------------------
// Fused residual add + LayerNorm. O = LN(X + Y0 [+ Y1]); optional split out.
// ---------------------------------------------------------------------------
__launch_bounds__(256)
__global__ void add_ln(const float* __restrict__ X, const float* __restrict__ Y0,
                       const float* __restrict__ Y1,
                       const float* __restrict__ gam, const float* __restrict__ bet,
                       float* __restrict__ O, bf16* __restrict__ Oh, bf16* __restrict__ Ol) {
  const int row = blockIdx.x, tid = threadIdx.x;
  const int lane = tid & 63, w = tid >> 6;
  __shared__ float red[4];
  float4 x = *reinterpret_cast<const float4*>(&X[(size_t)row * D_MODEL + tid * 4]);
  float4 y = *reinterpret_cast<const float4*>(&Y0[(size_t)row * D_MODEL + tid * 4]);
  float v0 = x.x + y.x, v1 = x.y + y.y, v2 = x.z + y.z, v3 = x.w + y.w;
  if (Y1) {
    float4 z = *reinterpret_cast<const float4*>(&Y1[(size_t)row * D_MODEL + tid * 4]);
    v0 += z.x; v1 += z.y; v2 += z.z; v3 += z.w;
  }
  float sm = v0 + v1 + v2 + v3;
#pragma unroll
  for (int off = 32; off >= 1; off >>= 1) sm += __shfl_xor(sm, off);
  if (lane == 0) red[w] = sm;
  __syncthreads();
  float mu = (red[0] + red[1] + red[2] + red[3]) * (1.f / D_MODEL);
  float d0 = v0 - mu, d1 = v1 - mu, d2 = v2 - mu, d3 = v3 - mu;
  float qs = d0 * d0 + d1 * d1 + d2 * d2 + d3 * d3;
#pragma unroll
  for (int off = 32; off >= 1; off >>= 1) qs += __shfl_xor(qs, off);
  __syncthreads();
  if (lane == 0) red[w] = qs;
  __syncthreads();
  float var = (red[0] + red[1] + red[2] + red[3]) * (1.f / D_MODEL);
  float rs = rsqrtf(var + 1e-5f);
  float4 gv = *reinterpret_cast<const float4*>(&gam[tid * 4]);
  float4 bv = *reinterpret_cast<const float4*>(&bet[tid * 4]);
  float4 o;
  o.x = d0 * rs * gv.x + bv.x;
  o.y = d1 * rs * gv.y + bv.y;
  o.z = d2 * rs * gv.z + bv.z;
  o.w = d3 * rs * gv.w + bv.w;
  *reinterpret_cast<float4*>(&O[(size_t)row * D_MODEL + tid * 4]) = o;
  if (Oh) {
    bf16x4 h4, l4;
    bfp s0 = fsplit(o.x); h4[0] = s0.h; l4[0] = s0.l;
    bfp s1 = fsplit(o.y); h4[1] = s1.h; l4[1] = s1.l;
    bfp s2 = fsplit(o.z); h4[2] = s2.h; l4[2] = s2.l;
    bfp s3 = fsplit(o.w); h4[3] = s3.h; l4[3] = s3.l;
    *reinterpret_cast<bf16x4*>(&Oh[(size_t)row * D_MODEL + tid * 4]) = h4;
    *reinterpret_cast<bf16x4*>(&Ol[(size_t)row * D_MODEL + tid * 4]) = l4;
  }
}

// ---------------------------------------------------------------------------
extern "C" void kernel_launch(void* const* d_in, const int* in_sizes, int n_in,
                              void* d_out, int out_size, void* d_ws, size_t ws_size,
                              hipStream_t stream) {
  (void)in_sizes; (void)n_in; (void)out_size; (void)ws_size;
  const float* tgt   = (const float*)d_in[0];
  const float* mem   = (const float*)d_in[1];
  const float* sa_wq = (const float*)d_in[2];
  const float* sa_bq = (const float*)d_in[3];
  const float* sa_wk = (const float*)d_in[4];
  const float* sa_bk = (const float*)d_in[5];
  const float* sa_wv = (const float*)d_in[6];
  const float* sa_bv = (const float*)d_in[7];
  const float* sa_wo = (const float*)d_in[8];
  const float* sa_bo = (const float*)d_in[9];
  const float* ca_wq = (const float*)d_in[10];
  const float* ca_bq = (const float*)d_in[11];
  const float* ca_wk = (const float*)d_in[12];
  const float* ca_bk = (const float*)d_in[13];
  const float* ca_wv = (const float*)d_in[14];
  const float* ca_bv = (const float*)d_in[15];
  const float* ca_wo = (const float*)d_in[16];
  const float* ca_bo = (const float*)d_in[17];
  const float* ff_w1 = (const float*)d_in[18];
  const float* ff_b1 = (const float*)d_in[19];
  const float* ff_w2 = (const float*)d_in[20];
  const float* ff_b2 = (const float*)d_in[21];
  const float* ln1g  = (const float*)d_in[22];
  const float* ln1b  = (const float*)d_in[23];
  const float* ln2g  = (const float*)d_in[24];
  const float* ln2b  = (const float*)d_in[25];
  const float* ln3g  = (const float*)d_in[26];
  const float* ln3b  = (const float*)d_in[27];
  float* out = (float*)d_out;

  char* base = (char*)d_ws;
  const size_t MB = 1u << 20;
  auto B16 = [&](size_t mb) { return (bf16*)(base + mb * MB); };
  auto F32 = [&](size_t mb) { return (float*)(base + mb * MB); };

  // weights (bf16, [N][K] transposed): 0-32 MB
  bf16 *qkvW_h  = B16(0);
  bf16 *sawo_h  = B16(6);
  bf16 *caqW_h  = B16(8);
  bf16 *cakvW_h = B16(10);
  bf16 *cawo_h  = B16(14);
  bf16 *w1_h    = B16(16);
  bf16 *w2_h    = B16(24);
  float* qkv_bias  = F32(32);
  float* cakv_bias = (float*)(base + 32 * MB + 65536);
  // activations
  bf16 *tgt_h = B16(33), *tgt_l = B16(41);    // later X2_hl
  bf16 *mem_h = B16(49), *mem_l = B16(57);
  bf16 *QKV   = B16(65);                      // [4096][3072] (SA)
  bf16 *Qb    = B16(65);                      // CA: [4096][1024]
  bf16 *KVb   = B16(73);                      // CA: [4096][2048]
  bf16 *HC_h  = B16(49), *HC_l = B16(81);     // FFN [4096][4096] (after CA)
  bf16 *CTX_h = B16(89), *CTX_l = B16(97);    // also X1_hl (sequenced)
  float* X1f  = F32(105);
  float* X2f  = F32(121);
  float* ACC  = F32(137);

  dim3 cb(32, 8);
  auto cast_w = [&](const float* W, int K, int N, bf16* th, float sc) {
    hipLaunchKernelGGL(wcast_t, dim3(K / 32, N / 32), cb, 0, stream, W, th, K, N, sc);
  };
  cast_w(sa_wq, 1024, 1024, qkvW_h, 1.f);
  cast_w(sa_wk, 1024, 1024, qkvW_h + (size_t)1024 * 1024, 0.125f);
  cast_w(sa_wv, 1024, 1024, qkvW_h + (size_t)2048 * 1024, 1.f);
  cast_w(sa_wo, 1024, 1024, sawo_h, 1.f);
  cast_w(ca_wq, 1024, 1024, caqW_h, 1.f);
  cast_w(ca_wk, 1024, 1024, cakvW_h, 0.125f);
  cast_w(ca_wv, 1024, 1024, cakvW_h + (size_t)1024 * 1024, 1.f);
  cast_w(ca_wo, 1024, 1024, cawo_h, 1.f);
  cast_w(ff_w1, 1024, 4096, w1_h, 1.f);
  cast_w(ff_w2, 4096, 1024, w2_h, 1.f);
  hipLaunchKernelGGL(scale_copy, dim3(4), dim3(256), 0, stream, sa_bq, qkv_bias, 1.f);
  hipLaunchKernelGGL(scale_copy, dim3(4), dim3(256), 0, stream, sa_bk, qkv_bias + 1024, 0.125f);
  hipLaunchKernelGGL(scale_copy, dim3(4), dim3(256), 0, stream, sa_bv, qkv_bias + 2048, 1.f);
  hipLaunchKernelGGL(scale_copy, dim3(4), dim3(256), 0, stream, ca_bk, cakv_bias, 0.125f);
  hipLaunchKernelGGL(scale_copy, dim3(4), dim3(256), 0, stream, ca_bv, cakv_bias + 1024, 1.f);
  hipLaunchKernelGGL(act_split, dim3(4096), dim3(256), 0, stream, tgt, tgt_h, tgt_l);
  hipLaunchKernelGGL(act_split, dim3(4096), dim3(256), 0, stream, mem, mem_h, mem_l);

  auto gemm = [&](const bf16* ah, const bf16* al, const bf16* bh,
                  const float* bias, float* cf, bf16* ch, bf16* cl,
                  int N, int K, int ldb, int flags, int Z) {
    hipLaunchKernelGGL(gemm_split, dim3(N / 128, 32, Z), dim3(256), 0, stream,
                       ah, al, bh, bias, cf, ch, cl, N, K, ldb, flags);
  };
  const size_t FBYTES = (size_t)M_ROWS * D_MODEL * 4;

  // ---- self-attention ----
  gemm(tgt_h, tgt_l, qkvW_h, qkv_bias, nullptr, QKV, nullptr, 3072, 1024, 1024, 4 | 16, 1);
  hipLaunchKernelGGL(attn_kernel, dim3(S_LEN / 128, 32), dim3(256), 0, stream,
                     QKV, QKV + 1024, QKV + 2048, 3072, 3072, CTX_h, CTX_l, 1);
  hipMemsetAsync(ACC, 0, FBYTES, stream);
  gemm(CTX_h, CTX_l, sawo_h, sa_bo, ACC, nullptr, nullptr, 1024, 1024, 1024, 2 | 16, 4);
  hipLaunchKernelGGL(add_ln, dim3(M_ROWS), dim3(256), 0, stream,
                     tgt, ACC, nullptr, ln1g, ln1b, X1f, CTX_h, CTX_l);

  // ---- cross-attention ----
  hipMemsetAsync(ACC, 0, FBYTES, stream);
  gemm(CTX_h, CTX_l, caqW_h, ca_bq, ACC, nullptr, nullptr, 1024, 1024, 1024, 2 | 16, 4);
  hipLaunchKernelGGL(cast_bf16, dim3(4096), dim3(256), 0, stream, ACC, Qb);
  gemm(mem_h, mem_l, cakvW_h, cakv_bias, nullptr, KVb, nullptr, 2048, 1024, 1024, 4 | 16, 1);
  hipLaunchKernelGGL(attn_kernel, dim3(S_LEN / 128, 32), dim3(256), 0, stream,
                     Qb, KVb, KVb + 1024, 1024, 2048, CTX_h, CTX_l, 0);
  hipMemsetAsync(ACC, 0, FBYTES, stream);
  gemm(CTX_h, CTX_l, cawo_h, ca_bo, ACC, nullptr, nullptr, 1024, 1024, 1024, 2 | 16, 4);
  hipLaunchKernelGGL(add_ln, dim3(M_ROWS), dim3(256), 0, stream,
                     X1f, ACC, nullptr, ln2g, ln2b, X2f, tgt_h, tgt_l);

  // ---- FFN: merged W1 (N=4096) + merged W2 (K=4096, z=4 atomic) ----
  gemm(tgt_h, tgt_l, w1_h, ff_b1, nullptr, HC_h, HC_l, 4096, 1024, 1024, 8 | 16 | 1, 1);
  hipMemsetAsync(ACC, 0, FBYTES, stream);
  gemm(HC_h, HC_l, w2_h, ff_b2, ACC, nullptr, nullptr, 1024, 4096, 4096, 2 | 16, 4);
  hipLaunchKernelGGL(add_ln, dim3(M_ROWS), dim3(256), 0, stream,
                     X2f, ACC, nullptr, ln3g, ln3b, out, nullptr, nullptr);
}

// Round 10
// 808.092 us; speedup vs baseline: 1.2606x; 1.2606x over previous
//
#include <hip/hip_runtime.h>
#include <cstdint>
#include <cstddef>

// DecoderBlock on MI355X (gfx950), round 10 (= round 8 kernel, 3rd submit; two
// GPUAcquisitionTimeouts prevented any measurement of this exact source).
// - 2-pass bf16 split GEMM (A = Ah+Al, W = bf16(W)), glds staging, 128x128.
// - XCD-aware bijective block swizzle (T1/m204) inside gemm_split: n-tiles
//   sharing an A-slice co-locate on one XCD -> A fetched once per XCD.
// - No atomics/memsets: z=2 K-split GEMMs write 2 fp32 partial planes,
//   summed in the 3-input add_ln.
// - Attention: QBLK=128, KVBLK=64, dbuf, swizzled K, stride-68 P relay,
//   K pre-scaled 1/8 at weight-cast, T13 defer-rescale, deferred l-reduce.

typedef __bf16 bf16;
typedef __attribute__((ext_vector_type(4))) float f32x4;
typedef __attribute__((ext_vector_type(8))) __bf16 bf16x8;
typedef __attribute__((ext_vector_type(4))) __bf16 bf16x4;
typedef __attribute__((ext_vector_type(2))) __bf16 bf16x2;

#define MFMA(a, b, c) __builtin_amdgcn_mfma_f32_16x16x32_bf16((a), (b), (c), 0, 0, 0)

constexpr int D_MODEL = 1024;
constexpr int S_LEN   = 2048;
constexpr int BATCH   = 2;
constexpr int M_ROWS  = S_LEN * BATCH;  // 4096

struct bfp { bf16 h, l; };
__device__ __forceinline__ bfp fsplit(float f) {
  bfp r;
  r.h = (bf16)f;
  r.l = (bf16)(f - (float)r.h);
  return r;
}

typedef const void __attribute__((address_space(1))) gas_void;
typedef void __attribute__((address_space(3))) las_void;
__device__ __forceinline__ void glds16(const void* g, void* l) {
  __builtin_amdgcn_global_load_lds((gas_void*)g, (las_void*)l, 16, 0, 0);
}

// ---------------------------------------------------------------------------
// Weight cast + transpose + scale: W[K][N] fp32 -> Th[N][K] bf16 * sc
// ---------------------------------------------------------------------------
__global__ void wcast_t(const float* __restrict__ W, bf16* __restrict__ Th,
                        int K, int N, float sc) {
  __shared__ float t[32][33];
  const int kt = blockIdx.x * 32, nt = blockIdx.y * 32;
  const int tx = threadIdx.x, ty = threadIdx.y;  // 32 x 8
#pragma unroll
  for (int i = 0; i < 4; ++i)
    t[ty * 4 + i][tx] = W[(size_t)(kt + ty * 4 + i) * N + nt + tx];
  __syncthreads();
#pragma unroll
  for (int i = 0; i < 4; ++i) {
    int n = nt + ty * 4 + i;
    Th[(size_t)n * K + kt + tx] = (bf16)(t[tx][ty * 4 + i] * sc);
  }
}

// ---------------------------------------------------------------------------
__global__ void scale_copy(const float* __restrict__ S, float* __restrict__ D,
                           float sc) {
  const int i = blockIdx.x * 256 + threadIdx.x;
  D[i] = S[i] * sc;
}

__global__ void act_split(const float* __restrict__ X, bf16* __restrict__ H,
                          bf16* __restrict__ L) {
  const size_t i = ((size_t)blockIdx.x * 256 + threadIdx.x) * 4;
  float4 v = *reinterpret_cast<const float4*>(&X[i]);
  bf16x4 h, l;
  bfp s0 = fsplit(v.x); h[0] = s0.h; l[0] = s0.l;
  bfp s1 = fsplit(v.y); h[1] = s1.h; l[1] = s1.l;
  bfp s2 = fsplit(v.z); h[2] = s2.h; l[2] = s2.l;
  bfp s3 = fsplit(v.w); h[3] = s3.h; l[3] = s3.l;
  *reinterpret_cast<bf16x4*>(&H[i]) = h;
  *reinterpret_cast<bf16x4*>(&L[i]) = l;
}

// ---------------------------------------------------------------------------
// 2-pass split GEMM with XCD-aware swizzle. A = Ah+Al [M][K] bf16,
// B = Bh [N][ldb] bf16 (transposed). flags: 1 relu, 4 bf16 out, 8 split out,
// 16 add bias (z-slice 0 only), 32 partial store to Cf + z*M*N.
// ---------------------------------------------------------------------------
__launch_bounds__(256)
__global__ void gemm_split(const bf16* __restrict__ Ah_g, const bf16* __restrict__ Al_g,
                           const bf16* __restrict__ Bh_g,
                           const float* __restrict__ bias,
                           float* Cf, bf16* Ch, bf16* Cl,
                           int N, int K, int ldb, int flags) {
  __shared__ bf16 sAh[4096], sAl[4096], sBh[4096];  // [128][32] each
  const int tid = threadIdx.x, ln = tid & 63, w = tid >> 6;
  const int g = ln >> 4, lr = ln & 15;
  const int wr = w >> 1, wc = w & 1;

  // XCD-aware bijective remap (nwg % 8 == 0 for all our launches).
  // XCD gets a contiguous run of s; s enumerates n fastest -> the n-tiles
  // sharing an A-slice co-reside on one XCD's L2.
  const int nx = gridDim.x, ny = gridDim.y, nz = gridDim.z;
  const int nwg = nx * ny * nz;
  const int o = blockIdx.x + nx * (blockIdx.y + ny * blockIdx.z);
  const int s = (o & 7) * (nwg >> 3) + (o >> 3);
  const int bx = s % nx;
  const int rest = s / nx;
  const int by = rest % ny;
  const int bz = rest / ny;

  const int m0 = by * 128, n0 = bx * 128;
  const int kz = K / nz;
  const int kbeg = bz * kz, kend = kbeg + kz;

  f32x4 acc[4][4] = {};

  for (int k0 = kbeg; k0 < kend; k0 += 32) {
    __syncthreads();
#pragma unroll
    for (int i = 0; i < 2; ++i) {
      const int r = w * 32 + i * 16 + (ln >> 2);
      const int co = (ln & 3) * 8;
      const int lb = (w * 32 + i * 16) * 32;
      glds16(Ah_g + (size_t)(m0 + r) * K + k0 + co, &sAh[lb]);
      glds16(Al_g + (size_t)(m0 + r) * K + k0 + co, &sAl[lb]);
      glds16(Bh_g + (size_t)(n0 + r) * ldb + k0 + co, &sBh[lb]);
    }
    __syncthreads();

    bf16x8 ah[4], al[4], bh[4];
#pragma unroll
    for (int mi = 0; mi < 4; ++mi) {
      const int r = wr * 64 + mi * 16 + lr;
      ah[mi] = *reinterpret_cast<const bf16x8*>(&sAh[r * 32 + g * 8]);
      al[mi] = *reinterpret_cast<const bf16x8*>(&sAl[r * 32 + g * 8]);
    }
#pragma unroll
    for (int ni = 0; ni < 4; ++ni) {
      const int r = wc * 64 + ni * 16 + lr;
      bh[ni] = *reinterpret_cast<const bf16x8*>(&sBh[r * 32 + g * 8]);
    }
#pragma unroll
    for (int mi = 0; mi < 4; ++mi)
#pragma unroll
      for (int ni = 0; ni < 4; ++ni) {
        acc[mi][ni] = MFMA(ah[mi], bh[ni], acc[mi][ni]);
        acc[mi][ni] = MFMA(al[mi], bh[ni], acc[mi][ni]);
      }
  }

  const size_t MN = (size_t)M_ROWS * N;
#pragma unroll
  for (int mi = 0; mi < 4; ++mi)
#pragma unroll
    for (int ni = 0; ni < 4; ++ni) {
      const int col = n0 + wc * 64 + ni * 16 + lr;
      const float bv = ((flags & 16) && bz == 0) ? bias[col] : 0.f;
#pragma unroll
      for (int r = 0; r < 4; ++r) {
        const int row = m0 + wr * 64 + mi * 16 + g * 4 + r;
        float v = acc[mi][ni][r] + bv;
        if (flags & 1) v = fmaxf(v, 0.f);
        const size_t off = (size_t)row * N + col;
        if (flags & 32) {
          Cf[(size_t)bz * MN + off] = v;
        } else if (flags & 4) {
          Ch[off] = (bf16)v;
        } else if (flags & 8) {
          bfp sp = fsplit(v);
          Ch[off] = sp.h;
          Cl[off] = sp.l;
        } else {
          Cf[off] = v;
        }
      }
    }
}

// ---------------------------------------------------------------------------
// Flash attention. bf16 in (K pre-scaled by 1/8), split-bf16 CTX out.
// Grid (S/128, BATCH*NHEAD), 256 thr. Wave w owns 32 q-rows q0 = qt*128+w*32.
// ---------------------------------------------------------------------------
__launch_bounds__(256)
__global__ void attn_kernel(const bf16* __restrict__ Qg, const bf16* __restrict__ Kg,
                            const bf16* __restrict__ Vg, int qs, int kvs,
                            bf16* __restrict__ Ch, bf16* __restrict__ Cl, int causal) {
  __shared__ bf16 Kl[2][64 * 64];   // swizzled, glds
  __shared__ bf16 Vt[2][64][72];    // [d][key]
  __shared__ bf16 Pl[4][32][68];    // per-wave P relay, stride 68
  const int tid = threadIdx.x, ln = tid & 63, w = tid >> 6;
  const int g = ln >> 4, lr = ln & 15;
  const int qt = blockIdx.x, bh = blockIdx.y;
  const int b = bh >> 4, h = bh & 15;
  const int q0 = qt * 128 + w * 32;

  const int krow8 = ln >> 3, d8 = ln & 7;   // K staging
  const int dq = tid >> 4, kp = tid & 15;   // V staging

  bf16x8 aq[2][2];
#pragma unroll
  for (int mf = 0; mf < 2; ++mf)
#pragma unroll
    for (int kk = 0; kk < 2; ++kk)
      aq[mf][kk] = *reinterpret_cast<const bf16x8*>(
          &Qg[((size_t)(q0 + mf * 16 + lr) * BATCH + b) * qs + h * 64 + kk * 32 + g * 8]);

  f32x4 acco[2][4] = {};
  float mrun[2][4], lrun[2][4];
#pragma unroll
  for (int mf = 0; mf < 2; ++mf)
#pragma unroll
    for (int r = 0; r < 4; ++r) { mrun[mf][r] = -1e30f; lrun[mf][r] = 0.f; }

  const int nkv = causal ? (qt * 2 + 2) : (S_LEN / 64);

  bf16x4 vreg[2][2];
  auto stageK = [&](int kv0, bf16* dst) {
#pragma unroll
    for (int i = 0; i < 2; ++i) {
      const int rbase = i * 32 + w * 8;
      const int row = rbase + krow8;
      glds16(Kg + (size_t)((kv0 + row) * BATCH + b) * kvs + h * 64 + ((d8 ^ (row & 7)) << 3),
             dst + rbase * 64);
    }
  };
  auto loadV = [&](int kv0) {
#pragma unroll
    for (int p = 0; p < 2; ++p) {
      const int k0v = p * 32 + kp * 2;
      vreg[p][0] = *reinterpret_cast<const bf16x4*>(
          &Vg[(size_t)((kv0 + k0v) * BATCH + b) * kvs + h * 64 + dq * 4]);
      vreg[p][1] = *reinterpret_cast<const bf16x4*>(
          &Vg[(size_t)((kv0 + k0v + 1) * BATCH + b) * kvs + h * 64 + dq * 4]);
    }
  };
  auto writeV = [&](int buf) {
#pragma unroll
    for (int p = 0; p < 2; ++p) {
      const int k0v = p * 32 + kp * 2;
#pragma unroll
      for (int i = 0; i < 4; ++i) {
        bf16x2 t2;
        t2[0] = vreg[p][0][i];
        t2[1] = vreg[p][1][i];
        *reinterpret_cast<bf16x2*>(&Vt[buf][dq * 4 + i][k0v]) = t2;
      }
    }
  };

  stageK(0, Kl[0]);
  loadV(0);
  writeV(0);
  __syncthreads();

  for (int kv = 0; kv < nkv; ++kv) {
    const int cur = kv & 1;
    const bool pre = (kv + 1 < nkv);
    if (pre) {  // issue next-tile loads early (T14)
      stageK((kv + 1) * 64, Kl[cur ^ 1]);
      loadV((kv + 1) * 64);
    }
    const int kv0 = kv * 64;

    if (!(causal && kv0 > q0 + 31)) {
      const char* kbase = (const char*)Kl[cur];
      // S = Q K^T (K pre-scaled by 1/8)
      f32x4 s[2][4];
      __builtin_amdgcn_s_setprio(1);
#pragma unroll
      for (int mf = 0; mf < 2; ++mf)
#pragma unroll
        for (int c = 0; c < 4; ++c) {
          f32x4 a = {};
#pragma unroll
          for (int kk = 0; kk < 2; ++kk) {
            bf16x8 bk = *reinterpret_cast<const bf16x8*>(
                kbase + (c * 16 + lr) * 128 + ((((kk << 2) + g) ^ (lr & 7)) << 4));
            a = MFMA(aq[mf][kk], bk, a);
          }
          s[mf][c] = a;
        }
      __builtin_amdgcn_s_setprio(0);

      if (causal && kv0 + 63 > q0) {
#pragma unroll
        for (int mf = 0; mf < 2; ++mf)
#pragma unroll
          for (int c = 0; c < 4; ++c) {
            const int key = kv0 + c * 16 + lr;
#pragma unroll
            for (int r = 0; r < 4; ++r)
              if (key > q0 + mf * 16 + g * 4 + r) s[mf][c][r] = -1e30f;
          }
      }

      // T13 defer-rescale: only rescale when some lane's local max grows >5
      float lm[2][4];
      bool need = false;
#pragma unroll
      for (int mf = 0; mf < 2; ++mf)
#pragma unroll
        for (int r = 0; r < 4; ++r) {
          lm[mf][r] = fmaxf(fmaxf(s[mf][0][r], s[mf][1][r]),
                            fmaxf(s[mf][2][r], s[mf][3][r]));
          need = need || (lm[mf][r] > mrun[mf][r] + 5.f);
        }
      if (__any(need)) {
#pragma unroll
        for (int mf = 0; mf < 2; ++mf)
#pragma unroll
          for (int r = 0; r < 4; ++r) {
            float mx = lm[mf][r];
#pragma unroll
            for (int off = 8; off >= 1; off >>= 1) mx = fmaxf(mx, __shfl_xor(mx, off));
            const float mnew = fmaxf(mrun[mf][r], mx);
            const float sf = __expf(mrun[mf][r] - mnew);
            lrun[mf][r] *= sf;
            mrun[mf][r] = mnew;
#pragma unroll
            for (int t = 0; t < 4; ++t) acco[mf][t][r] *= sf;
          }
      }
#pragma unroll
      for (int mf = 0; mf < 2; ++mf)
#pragma unroll
        for (int r = 0; r < 4; ++r) {
          float pv[4], ps = 0.f;
#pragma unroll
          for (int c = 0; c < 4; ++c) { pv[c] = __expf(s[mf][c][r] - mrun[mf][r]); ps += pv[c]; }
          lrun[mf][r] += ps;
#pragma unroll
          for (int c = 0; c < 4; ++c) Pl[w][mf * 16 + g * 4 + r][c * 16 + lr] = (bf16)pv[c];
        }

      // O += P V
      __builtin_amdgcn_s_setprio(1);
#pragma unroll
      for (int mf = 0; mf < 2; ++mf) {
        bf16x8 ap0 = *reinterpret_cast<const bf16x8*>(&Pl[w][mf * 16 + lr][g * 8]);
        bf16x8 ap1 = *reinterpret_cast<const bf16x8*>(&Pl[w][mf * 16 + lr][32 + g * 8]);
#pragma unroll
        for (int t = 0; t < 4; ++t) {
          bf16x8 v0 = *reinterpret_cast<const bf16x8*>(&Vt[cur][t * 16 + lr][g * 8]);
          bf16x8 v1 = *reinterpret_cast<const bf16x8*>(&Vt[cur][t * 16 + lr][32 + g * 8]);
          acco[mf][t] = MFMA(ap0, v0, acco[mf][t]);
          acco[mf][t] = MFMA(ap1, v1, acco[mf][t]);
        }
      }
      __builtin_amdgcn_s_setprio(0);
    }

    if (pre) writeV(cur ^ 1);  // write-late
    __syncthreads();
  }

  // epilogue: finish l reduction, normalize, split-store
#pragma unroll
  for (int mf = 0; mf < 2; ++mf)
#pragma unroll
    for (int r = 0; r < 4; ++r) {
      float l = lrun[mf][r];
#pragma unroll
      for (int off = 8; off >= 1; off >>= 1) l += __shfl_xor(l, off);
      lrun[mf][r] = 1.f / l;
    }
#pragma unroll
  for (int mf = 0; mf < 2; ++mf)
#pragma unroll
    for (int t = 0; t < 4; ++t)
#pragma unroll
      for (int r = 0; r < 4; ++r) {
        const int srow = q0 + mf * 16 + g * 4 + r;
        const size_t off = (size_t)(srow * BATCH + b) * D_MODEL + h * 64 + t * 16 + lr;
        const float v = acco[mf][t][r] * lrun[mf][r];
        bfp sp = fsplit(v);
        Ch[off] = sp.h;
        Cl[off] = sp.l;
      }
}

// ---------------------------------------------------------------------------
// Fused residual add + LayerNorm. O = LN(X + Y0 [+ Y1]); optional split out.
// ---------------------------------------------------------------------------
__launch_bounds__(256)
__global__ void add_ln(const float* __restrict__ X, const float* __restrict__ Y0,
                       const float* __restrict__ Y1,
                       const float* __restrict__ gam, const float* __restrict__ bet,
                       float* __restrict__ O, bf16* __restrict__ Oh, bf16* __restrict__ Ol) {
  const int row = blockIdx.x, tid = threadIdx.x;
  const int lane = tid & 63, w = tid >> 6;
  __shared__ float red[4];
  float4 x = *reinterpret_cast<const float4*>(&X[(size_t)row * D_MODEL + tid * 4]);
  float4 y = *reinterpret_cast<const float4*>(&Y0[(size_t)row * D_MODEL + tid * 4]);
  float v0 = x.x + y.x, v1 = x.y + y.y, v2 = x.z + y.z, v3 = x.w + y.w;
  if (Y1) {
    float4 z = *reinterpret_cast<const float4*>(&Y1[(size_t)row * D_MODEL + tid * 4]);
    v0 += z.x; v1 += z.y; v2 += z.z; v3 += z.w;
  }
  float sm = v0 + v1 + v2 + v3;
#pragma unroll
  for (int off = 32; off >= 1; off >>= 1) sm += __shfl_xor(sm, off);
  if (lane == 0) red[w] = sm;
  __syncthreads();
  float mu = (red[0] + red[1] + red[2] + red[3]) * (1.f / D_MODEL);
  float d0 = v0 - mu, d1 = v1 - mu, d2 = v2 - mu, d3 = v3 - mu;
  float qs = d0 * d0 + d1 * d1 + d2 * d2 + d3 * d3;
#pragma unroll
  for (int off = 32; off >= 1; off >>= 1) qs += __shfl_xor(qs, off);
  __syncthreads();
  if (lane == 0) red[w] = qs;
  __syncthreads();
  float var = (red[0] + red[1] + red[2] + red[3]) * (1.f / D_MODEL);
  float rs = rsqrtf(var + 1e-5f);
  float4 gv = *reinterpret_cast<const float4*>(&gam[tid * 4]);
  float4 bv = *reinterpret_cast<const float4*>(&bet[tid * 4]);
  float4 o;
  o.x = d0 * rs * gv.x + bv.x;
  o.y = d1 * rs * gv.y + bv.y;
  o.z = d2 * rs * gv.z + bv.z;
  o.w = d3 * rs * gv.w + bv.w;
  *reinterpret_cast<float4*>(&O[(size_t)row * D_MODEL + tid * 4]) = o;
  if (Oh) {
    bf16x4 h4, l4;
    bfp s0 = fsplit(o.x); h4[0] = s0.h; l4[0] = s0.l;
    bfp s1 = fsplit(o.y); h4[1] = s1.h; l4[1] = s1.l;
    bfp s2 = fsplit(o.z); h4[2] = s2.h; l4[2] = s2.l;
    bfp s3 = fsplit(o.w); h4[3] = s3.h; l4[3] = s3.l;
    *reinterpret_cast<bf16x4*>(&Oh[(size_t)row * D_MODEL + tid * 4]) = h4;
    *reinterpret_cast<bf16x4*>(&Ol[(size_t)row * D_MODEL + tid * 4]) = l4;
  }
}

// ---------------------------------------------------------------------------
extern "C" void kernel_launch(void* const* d_in, const int* in_sizes, int n_in,
                              void* d_out, int out_size, void* d_ws, size_t ws_size,
                              hipStream_t stream) {
  (void)in_sizes; (void)n_in; (void)out_size; (void)ws_size;
  const float* tgt   = (const float*)d_in[0];
  const float* mem   = (const float*)d_in[1];
  const float* sa_wq = (const float*)d_in[2];
  const float* sa_bq = (const float*)d_in[3];
  const float* sa_wk = (const float*)d_in[4];
  const float* sa_bk = (const float*)d_in[5];
  const float* sa_wv = (const float*)d_in[6];
  const float* sa_bv = (const float*)d_in[7];
  const float* sa_wo = (const float*)d_in[8];
  const float* sa_bo = (const float*)d_in[9];
  const float* ca_wq = (const float*)d_in[10];
  const float* ca_bq = (const float*)d_in[11];
  const float* ca_wk = (const float*)d_in[12];
  const float* ca_bk = (const float*)d_in[13];
  const float* ca_wv = (const float*)d_in[14];
  const float* ca_bv = (const float*)d_in[15];
  const float* ca_wo = (const float*)d_in[16];
  const float* ca_bo = (const float*)d_in[17];
  const float* ff_w1 = (const float*)d_in[18];
  const float* ff_b1 = (const float*)d_in[19];
  const float* ff_w2 = (const float*)d_in[20];
  const float* ff_b2 = (const float*)d_in[21];
  const float* ln1g  = (const float*)d_in[22];
  const float* ln1b  = (const float*)d_in[23];
  const float* ln2g  = (const float*)d_in[24];
  const float* ln2b  = (const float*)d_in[25];
  const float* ln3g  = (const float*)d_in[26];
  const float* ln3b  = (const float*)d_in[27];
  float* out = (float*)d_out;

  char* base = (char*)d_ws;
  const size_t MB = 1u << 20;
  auto B16 = [&](size_t mb) { return (bf16*)(base + mb * MB); };
  auto F32 = [&](size_t mb) { return (float*)(base + mb * MB); };

  // weights (bf16, [N][K] transposed): 0-32 MB
  bf16 *qkvW_h  = B16(0);
  bf16 *sawo_h  = B16(6);
  bf16 *caqW_h  = B16(8);
  bf16 *cakvW_h = B16(10);
  bf16 *cawo_h  = B16(14);
  bf16 *w1_h    = B16(16);
  bf16 *w2_h    = B16(24);
  float* qkv_bias  = F32(32);
  float* cakv_bias = (float*)(base + 32 * MB + 65536);
  // activations
  bf16 *tgt_h = B16(33), *tgt_l = B16(41);    // later X2_hl
  bf16 *mem_h = B16(49), *mem_l = B16(57);
  bf16 *QKV   = B16(65);                      // [4096][3072] (SA)
  bf16 *Qb    = B16(65);                      // CA: [4096][1024]
  bf16 *KVb   = B16(73);                      // CA: [4096][2048]
  bf16 *HC_h  = B16(49), *HC_l = B16(81);     // FFN [4096][4096] (after CA)
  bf16 *CTX_h = B16(89), *CTX_l = B16(97);    // also X1_hl (sequenced)
  float* X1f  = F32(105);
  float* X2f  = F32(121);
  float* ACC  = F32(137);                     // z=0 partial
  float* ACC2 = F32(153);                     // z=1 partial (contiguous)

  dim3 cb(32, 8);
  auto cast_w = [&](const float* W, int K, int N, bf16* th, float sc) {
    hipLaunchKernelGGL(wcast_t, dim3(K / 32, N / 32), cb, 0, stream, W, th, K, N, sc);
  };
  cast_w(sa_wq, 1024, 1024, qkvW_h, 1.f);
  cast_w(sa_wk, 1024, 1024, qkvW_h + (size_t)1024 * 1024, 0.125f);
  cast_w(sa_wv, 1024, 1024, qkvW_h + (size_t)2048 * 1024, 1.f);
  cast_w(sa_wo, 1024, 1024, sawo_h, 1.f);
  cast_w(ca_wq, 1024, 1024, caqW_h, 1.f);
  cast_w(ca_wk, 1024, 1024, cakvW_h, 0.125f);
  cast_w(ca_wv, 1024, 1024, cakvW_h + (size_t)1024 * 1024, 1.f);
  cast_w(ca_wo, 1024, 1024, cawo_h, 1.f);
  cast_w(ff_w1, 1024, 4096, w1_h, 1.f);
  cast_w(ff_w2, 4096, 1024, w2_h, 1.f);
  hipLaunchKernelGGL(scale_copy, dim3(4), dim3(256), 0, stream, sa_bq, qkv_bias, 1.f);
  hipLaunchKernelGGL(scale_copy, dim3(4), dim3(256), 0, stream, sa_bk, qkv_bias + 1024, 0.125f);
  hipLaunchKernelGGL(scale_copy, dim3(4), dim3(256), 0, stream, sa_bv, qkv_bias + 2048, 1.f);
  hipLaunchKernelGGL(scale_copy, dim3(4), dim3(256), 0, stream, ca_bk, cakv_bias, 0.125f);
  hipLaunchKernelGGL(scale_copy, dim3(4), dim3(256), 0, stream, ca_bv, cakv_bias + 1024, 1.f);
  hipLaunchKernelGGL(act_split, dim3(4096), dim3(256), 0, stream, tgt, tgt_h, tgt_l);
  hipLaunchKernelGGL(act_split, dim3(4096), dim3(256), 0, stream, mem, mem_h, mem_l);

  auto gemm = [&](const bf16* ah, const bf16* al, const bf16* bh,
                  const float* bias, float* cf, bf16* ch, bf16* cl,
                  int N, int K, int ldb, int flags, int Z) {
    hipLaunchKernelGGL(gemm_split, dim3(N / 128, 32, Z), dim3(256), 0, stream,
                       ah, al, bh, bias, cf, ch, cl, N, K, ldb, flags);
  };

  // ---- self-attention ----
  gemm(tgt_h, tgt_l, qkvW_h, qkv_bias, nullptr, QKV, nullptr, 3072, 1024, 1024, 4 | 16, 1);
  hipLaunchKernelGGL(attn_kernel, dim3(S_LEN / 128, 32), dim3(256), 0, stream,
                     QKV, QKV + 1024, QKV + 2048, 3072, 3072, CTX_h, CTX_l, 1);
  gemm(CTX_h, CTX_l, sawo_h, sa_bo, ACC, nullptr, nullptr, 1024, 1024, 1024, 32 | 16, 2);
  hipLaunchKernelGGL(add_ln, dim3(M_ROWS), dim3(256), 0, stream,
                     tgt, ACC, ACC2, ln1g, ln1b, X1f, CTX_h, CTX_l);

  // ---- cross-attention ----
  gemm(CTX_h, CTX_l, caqW_h, ca_bq, nullptr, Qb, nullptr, 1024, 1024, 1024, 4 | 16, 1);
  gemm(mem_h, mem_l, cakvW_h, cakv_bias, nullptr, KVb, nullptr, 2048, 1024, 1024, 4 | 16, 1);
  hipLaunchKernelGGL(attn_kernel, dim3(S_LEN / 128, 32), dim3(256), 0, stream,
                     Qb, KVb, KVb + 1024, 1024, 2048, CTX_h, CTX_l, 0);
  gemm(CTX_h, CTX_l, cawo_h, ca_bo, ACC, nullptr, nullptr, 1024, 1024, 1024, 32 | 16, 2);
  hipLaunchKernelGGL(add_ln, dim3(M_ROWS), dim3(256), 0, stream,
                     X1f, ACC, ACC2, ln2g, ln2b, X2f, tgt_h, tgt_l);

  // ---- FFN: merged W1 (N=4096) + W2 (K=4096, z=2 partial stores) ----
  gemm(tgt_h, tgt_l, w1_h, ff_b1, nullptr, HC_h, HC_l, 4096, 1024, 1024, 8 | 16 | 1, 1);
  gemm(HC_h, HC_l, w2_h, ff_b2, ACC, nullptr, nullptr, 1024, 4096, 4096, 32 | 16, 2);
  hipLaunchKernelGGL(add_ln, dim3(M_ROWS), dim3(256), 0, stream,
                     X2f, ACC, ACC2, ln3g, ln3b, out, nullptr, nullptr);
}